// Round 4
// baseline (380.092 us; speedup 1.0000x reference)
//
#include <hip/hip_runtime.h>
#include <hip/hip_bf16.h>
#include <cstdint>
#include <cstddef>

// Problem constants (fixed by the reference)
#define TDIM 1024
#define HDIM 1024
#define FDIM 2048
#define NEXP 8
#define NENT 2048   // T * K

typedef __bf16 bf16_t;
typedef __bf16 bf16x4 __attribute__((ext_vector_type(4)));
typedef __bf16 bf16x8 __attribute__((ext_vector_type(8)));
typedef float  f32x4  __attribute__((ext_vector_type(4)));

#define H_ELEMS ((size_t)TDIM*HDIM)   // 1048576

// ---------------- workspace layout (bytes) ----------------
#define WB_OFFSETS 0                                   // int[16]
#define WB_ETOK    64
#define WB_ESCALE  (WB_ETOK + NENT*4)
#define WB_ACT     16512                               // bf16[NENT][FDIM] = 8 MB
#define WB_H       (WB_ACT + (size_t)NENT*FDIM*2)      // bf16[T][H] = 2 MB

__device__ __forceinline__ void gload16(const void* g, void* l) {
  __builtin_amdgcn_global_load_lds((const __attribute__((address_space(1))) void*)g,
                                   (__attribute__((address_space(3))) void*)l, 16, 0, 0);
}

__device__ __forceinline__ bf16x8 cvt8(const float4 a, const float4 b) {
  bf16x8 o;
  o[0]=(bf16_t)a.x; o[1]=(bf16_t)a.y; o[2]=(bf16_t)a.z; o[3]=(bf16_t)a.w;
  o[4]=(bf16_t)b.x; o[5]=(bf16_t)b.y; o[6]=(bf16_t)b.z; o[7]=(bf16_t)b.w;
  return o;
}

// 3-bit bank swizzle: seg position = seg ^ (row&3) ^ ((row>>2)&3).
__device__ __forceinline__ int segswz(int seg, int row) {
  return seg ^ (row & 3) ^ ((row >> 2) & 3);
}

// ---------------- routing (single block, one launch) ----------------
__global__ void route_all(const int* __restrict__ sel, const float* __restrict__ scal,
                          int* __restrict__ offsets, int* __restrict__ etok,
                          float* __restrict__ escale) {
  __shared__ int cnt[NEXP], cnt2[NEXP], offs[NEXP+1];
  const int t = threadIdx.x;    // 256 threads, 8 entries each
  if (t < NEXP) { cnt[t] = 0; cnt2[t] = 0; }
  __syncthreads();
  int e8[8];
  #pragma unroll
  for (int q = 0; q < 8; q++) {
    int i = t*8 + q;
    e8[q] = sel[i];
    atomicAdd(&cnt[e8[q]], 1);
  }
  __syncthreads();
  if (t == 0) {
    int s = 0;
    for (int e = 0; e < NEXP; e++) { offs[e] = s; offsets[e] = s; s += cnt[e]; }
    offs[NEXP] = s; offsets[NEXP] = s;
  }
  __syncthreads();
  #pragma unroll
  for (int q = 0; q < 8; q++) {
    int i = t*8 + q;
    int e = e8[q];
    int pos = offs[e] + atomicAdd(&cnt2[e], 1);
    etok[pos]   = i >> 1;       // TOPK == 2
    escale[pos] = scal[i];
  }
}

// ---------------- hidden fp32 -> bf16 ----------------
__global__ void convert_h(const float* __restrict__ h, bf16_t* __restrict__ hbf) {
  size_t idx = ((size_t)blockIdx.x*256 + threadIdx.x) * 8;
  float4 v0 = ((const float4*)(h + idx))[0];
  float4 v1 = ((const float4*)(h + idx))[1];
  *(bf16x8*)(hbf + idx) = cvt8(v0, v1);
}

// ======== v9: BM=256 — halve the weight (B) stream ========
// All v6-v8 schedule changes were ~neutral while FETCH_SIZE stayed constant:
// the gemms are bound by the B-stream (fp32 weights) through the L2-miss
// path, read once per 128-row m-tile (2x per expert). BM=256 covers a whole
// expert (nt~256) in one m-tile -> each weight element loaded ~once.
// 512 thr = 8 waves (4m x 2n), per-wave tile unchanged (64m). 1 block/CU,
// 8 waves/CU (same as before). Depth-2 B reg prefetch pipeline kept.

// GEMM1: act = silu(x@w1g^T + b1g) * (x@w1l^T + b1l)
__global__ __launch_bounds__(512, 1) void gemm1_v9(
    const bf16_t* __restrict__ hbf, const float* __restrict__ w1,
    const float* __restrict__ b1, const int* __restrict__ offsets,
    const int* __restrict__ etok, bf16_t* __restrict__ act)
{
  const int e   = blockIdx.y;
  const int off = offsets[e];
  const int nt  = offsets[e+1] - off;
  const int m0  = blockIdx.z * 256;
  if (m0 >= nt) return;
  const int n0  = blockIdx.x * 64;

  __shared__ __align__(16) bf16_t As[2][256*32];     // 32 KB
  __shared__ __align__(16) bf16_t Bs[2][2*64*32];    // [buf][gate|lin] 16 KB

  const int tid  = threadIdx.x;
  const int w    = tid >> 6, lane = tid & 63;        // 8 waves
  const int quad = lane >> 4, lr = lane & 15;
  const int wm   = w >> 1,  wn = w & 1;              // 4m x 2n

  // ---- A staging: inst i covers LDS rows [i*128 + w*16, +16) ----
  const bf16_t* asrc0; const bf16_t* asrc1;
  int arow0, arow1;
  {
    const int r0 = 0*128 + w*16 + (lane >> 2);
    const int r1 = 1*128 + w*16 + (lane >> 2);
    const int s0 = segswz(lane & 3, r0);
    const int s1 = segswz(lane & 3, r1);
    int e0 = m0 + r0; if (e0 > nt-1) e0 = nt-1;   // clamp; masked in epilogue
    int e1 = m0 + r1; if (e1 > nt-1) e1 = nt-1;
    asrc0 = hbf + (size_t)etok[off + e0]*HDIM + s0*8;
    asrc1 = hbf + (size_t)etok[off + e1]*HDIM + s1*8;
    arow0 = (0*128 + w*16)*32;                    // + lane*16B implicit
    arow1 = (1*128 + w*16)*32;
  }

  // ---- B staging: 512 thr cover gate(256 slots) + lin(256 slots) ----
  // gl = tid>>8 (0 gate, 1 lin); st = tid&255: row st>>2, seg st&3.
  const int gl = tid >> 8, st = tid & 255;
  const int br = st >> 2, bsg = st & 3;
  const float* bsrc = w1 + ((size_t)e*2*FDIM + (size_t)gl*FDIM + (size_t)(n0 + br))*HDIM + bsg*8;
  const int bidx = gl*(64*32) + br*32 + (segswz(bsg, br) << 3);

  // ---- loop-invariant fragment LDS offsets ----
  int aoff[4], boff[2];
  #pragma unroll
  for (int i = 0; i < 4; i++) {
    const int r = wm*64 + i*16 + lr;
    aoff[i] = r*32 + (segswz(quad, r) << 3);
  }
  #pragma unroll
  for (int j = 0; j < 2; j++) {
    const int r = wn*32 + j*16 + lr;
    boff[j] = r*32 + (segswz(quad, r) << 3);
  }

  f32x4 accg[4][2] = {}, accl[4][2] = {};
  float4 b4[2][2];               // depth-2 ping-pong B regs (one row-seg each)

#define G1_LOADB(SET, K0)                                                     \
  { const float4* p_ = (const float4*)(bsrc + (K0));                          \
    b4[SET][0]=p_[0]; b4[SET][1]=p_[1]; }

#define G1_WRITEB(NXT, SET)                                                   \
  { *(bf16x8*)&Bs[NXT][bidx] = cvt8(b4[SET][0], b4[SET][1]); }

#define G1_MFMA(CUR)                                                          \
  { bf16x8 af[4], gf[2], lf[2];                                               \
    _Pragma("unroll")                                                         \
    for (int i = 0; i < 4; i++) af[i] = *(const bf16x8*)&As[CUR][aoff[i]];    \
    _Pragma("unroll")                                                         \
    for (int j = 0; j < 2; j++) {                                             \
      gf[j] = *(const bf16x8*)&Bs[CUR][boff[j]];                              \
      lf[j] = *(const bf16x8*)&Bs[CUR][64*32 + boff[j]];                      \
    }                                                                         \
    _Pragma("unroll")                                                         \
    for (int i = 0; i < 4; i++)                                               \
      _Pragma("unroll")                                                       \
      for (int j = 0; j < 2; j++) {                                           \
        accg[i][j] = __builtin_amdgcn_mfma_f32_16x16x32_bf16(af[i], gf[j], accg[i][j], 0, 0, 0); \
        accl[i][j] = __builtin_amdgcn_mfma_f32_16x16x32_bf16(af[i], lf[j], accl[i][j], 0, 0, 0); \
      } }

  // ---- prologue: tile0 -> buf0; B(1)->set0, B(2)->set1 in flight ----
  G1_LOADB(0, 0);                                // B(0) -> set0, 2 vm
  __builtin_amdgcn_sched_barrier(0);
  gload16(asrc0 + 0, &As[0][arow0]);             // A(0), 2 vm
  gload16(asrc1 + 0, &As[0][arow1]);
  __builtin_amdgcn_sched_barrier(0);
  G1_WRITEB(0, 0);                               // compiler drains B(0) regs
  G1_LOADB(0, 32);                               // B(1) -> set0, 2 vm
  G1_LOADB(1, 64);                               // B(2) -> set1, 2 vm
  asm volatile("s_waitcnt vmcnt(4) lgkmcnt(0)" ::: "memory");  // A(0) done
  __builtin_amdgcn_sched_barrier(0);
  __builtin_amdgcn_s_barrier();
  __builtin_amdgcn_sched_barrier(0);

  // steady step at tile t: write B(t+1) from SET (loaded t-2), stage A(t+1),
  // issue B(t+3) -> SET, compute tile t. Wait vmcnt(2): drains B(t-1)+A,
  // leaves this iter's 2 B-loads in flight.
#define G1_STEP(CUR, SET)                                                     \
  { G1_WRITEB((CUR)^1, SET);                                                  \
    __builtin_amdgcn_sched_barrier(0);                                        \
    gload16(asrc0 + k0 + 32, &As[(CUR)^1][arow0]);                            \
    gload16(asrc1 + k0 + 32, &As[(CUR)^1][arow1]);                            \
    __builtin_amdgcn_sched_barrier(0);                                        \
    G1_LOADB(SET, k0 + 96);                                                   \
    __builtin_amdgcn_sched_barrier(0);                                        \
    G1_MFMA(CUR);                                                             \
    asm volatile("s_waitcnt vmcnt(2) lgkmcnt(0)" ::: "memory");               \
    __builtin_amdgcn_sched_barrier(0);                                        \
    __builtin_amdgcn_s_barrier();                                             \
    __builtin_amdgcn_sched_barrier(0);                                        \
    k0 += 32; }

  int k0 = 0;
  while (k0 < 896) {              // t = 0..27 (pairs)
    G1_STEP(0, 0);
    G1_STEP(1, 1);
  }
  G1_STEP(0, 0);                  // t = 28: loads B(31) at k0+96 = 992
  // t = 29 (CUR = 1): write B(30) from set1, stage A(30), no B-load
  G1_WRITEB(0, 1);
  __builtin_amdgcn_sched_barrier(0);
  gload16(asrc0 + 960, &As[0][arow0]);
  gload16(asrc1 + 960, &As[0][arow1]);
  __builtin_amdgcn_sched_barrier(0);
  G1_MFMA(1);
  asm volatile("s_waitcnt vmcnt(0) lgkmcnt(0)" ::: "memory");
  __builtin_amdgcn_sched_barrier(0);
  __builtin_amdgcn_s_barrier();
  __builtin_amdgcn_sched_barrier(0);
  // t = 30 (CUR = 0): write B(31) from set0, stage A(31)
  G1_WRITEB(1, 0);
  __builtin_amdgcn_sched_barrier(0);
  gload16(asrc0 + 992, &As[1][arow0]);
  gload16(asrc1 + 992, &As[1][arow1]);
  __builtin_amdgcn_sched_barrier(0);
  G1_MFMA(0);
  asm volatile("s_waitcnt vmcnt(0) lgkmcnt(0)" ::: "memory");
  __builtin_amdgcn_sched_barrier(0);
  __builtin_amdgcn_s_barrier();
  __builtin_amdgcn_sched_barrier(0);
  // t = 31
  G1_MFMA(1);

#undef G1_STEP
#undef G1_MFMA
#undef G1_WRITEB
#undef G1_LOADB

  // epilogue: bias + silu(gate)*lin -> act (bf16)
  #pragma unroll
  for (int j = 0; j < 2; j++) {
    const int f = n0 + wn*32 + j*16 + lr;
    const float bg_ = b1[e*2*FDIM + f];
    const float bl_ = b1[e*2*FDIM + FDIM + f];
    #pragma unroll
    for (int i = 0; i < 4; i++) {
      #pragma unroll
      for (int r = 0; r < 4; r++) {
        const int m = wm*64 + i*16 + quad*4 + r;
        if (m0 + m < nt) {
          const float g = accg[i][j][r] + bg_;
          const float l = accl[i][j][r] + bl_;
          const float s = g / (1.f + __expf(-g)) * l;
          act[(size_t)(off + m0 + m)*FDIM + f] = (bf16_t)s;
        }
      }
    }
  }
}

// GEMM2: y = act @ w2^T + b2; out[token] += scale * y  (atomic, split-K x4)
__global__ __launch_bounds__(512, 1) void gemm2_v9(
    const bf16_t* __restrict__ act, const float* __restrict__ w2,
    const float* __restrict__ b2, const int* __restrict__ offsets,
    const int* __restrict__ etok, const float* __restrict__ escale,
    float* __restrict__ out)
{
  const int e   = blockIdx.y;
  const int off = offsets[e];
  const int nt  = offsets[e+1] - off;
  const int m0  = blockIdx.z * 256;
  if (m0 >= nt) return;
  const int n0  = (blockIdx.x >> 2) * 128;
  const int kc  = blockIdx.x & 3;
  const int kbeg = kc * (FDIM/4);          // 512-chunk, 16 iters

  __shared__ __align__(16) bf16_t As[2][256*32];     // 32 KB
  __shared__ __align__(16) bf16_t Bs[2][128*32];     // 16 KB

  const int tid  = threadIdx.x;
  const int w    = tid >> 6, lane = tid & 63;        // 8 waves
  const int quad = lane >> 4, lr = lane & 15;
  const int wm   = w >> 1,  wn = w & 1;              // 4m x 2n (64m x 64n)

  const bf16_t* asrc0; const bf16_t* asrc1;
  int arow0, arow1;
  {
    const int r0 = 0*128 + w*16 + (lane >> 2);
    const int r1 = 1*128 + w*16 + (lane >> 2);
    const int s0 = segswz(lane & 3, r0);
    const int s1 = segswz(lane & 3, r1);
    int e0 = m0 + r0; if (e0 > nt-1) e0 = nt-1;
    int e1 = m0 + r1; if (e1 > nt-1) e1 = nt-1;
    asrc0 = act + (size_t)(off + e0)*FDIM + kbeg + s0*8;
    asrc1 = act + (size_t)(off + e1)*FDIM + kbeg + s1*8;
    arow0 = (0*128 + w*16)*32;
    arow1 = (1*128 + w*16)*32;
  }

  // B staging: 512 thr cover 128 rows x 4 segs, one slot each
  const int br = tid >> 2, bsg = tid & 3;
  const float* bsrc = w2 + ((size_t)e*HDIM + (size_t)(n0 + br))*FDIM + kbeg + bsg*8;
  const int bidx = br*32 + (segswz(bsg, br) << 3);

  int aoff[4], boff[4];
  #pragma unroll
  for (int i = 0; i < 4; i++) {
    const int r = wm*64 + i*16 + lr;
    aoff[i] = r*32 + (segswz(quad, r) << 3);
  }
  #pragma unroll
  for (int j = 0; j < 4; j++) {
    const int r = wn*64 + j*16 + lr;
    boff[j] = r*32 + (segswz(quad, r) << 3);
  }

  f32x4 acc[4][4] = {};
  float4 b4[2][2];               // depth-2 ping-pong B regs

#define G2_LOADB(SET, K0)                                                     \
  { const float4* p_ = (const float4*)(bsrc + (K0));                          \
    b4[SET][0]=p_[0]; b4[SET][1]=p_[1]; }

#define G2_WRITEB(NXT, SET)                                                   \
  { *(bf16x8*)&Bs[NXT][bidx] = cvt8(b4[SET][0], b4[SET][1]); }

#define G2_MFMA(CUR)                                                          \
  { bf16x8 af[4], bfr[4];                                                     \
    _Pragma("unroll")                                                         \
    for (int i = 0; i < 4; i++) af[i] = *(const bf16x8*)&As[CUR][aoff[i]];    \
    _Pragma("unroll")                                                         \
    for (int j = 0; j < 4; j++) bfr[j] = *(const bf16x8*)&Bs[CUR][boff[j]];   \
    _Pragma("unroll")                                                         \
    for (int i = 0; i < 4; i++)                                               \
      _Pragma("unroll")                                                       \
      for (int j = 0; j < 4; j++)                                             \
        acc[i][j] = __builtin_amdgcn_mfma_f32_16x16x32_bf16(af[i], bfr[j], acc[i][j], 0, 0, 0); }

  // ---- prologue ----
  G2_LOADB(0, 0);                                // B(0) -> set0, 2 vm
  __builtin_amdgcn_sched_barrier(0);
  gload16(asrc0 + 0, &As[0][arow0]);             // A(0), 2 vm
  gload16(asrc1 + 0, &As[0][arow1]);
  __builtin_amdgcn_sched_barrier(0);
  G2_WRITEB(0, 0);                               // compiler drains B(0) regs
  G2_LOADB(0, 32);                               // B(1) -> set0
  G2_LOADB(1, 64);                               // B(2) -> set1
  asm volatile("s_waitcnt vmcnt(4) lgkmcnt(0)" ::: "memory");  // A(0) done
  __builtin_amdgcn_sched_barrier(0);
  __builtin_amdgcn_s_barrier();
  __builtin_amdgcn_sched_barrier(0);

#define G2_STEP(CUR, SET)                                                     \
  { G2_WRITEB((CUR)^1, SET);                                                  \
    __builtin_amdgcn_sched_barrier(0);                                        \
    gload16(asrc0 + k0 + 32, &As[(CUR)^1][arow0]);                            \
    gload16(asrc1 + k0 + 32, &As[(CUR)^1][arow1]);                            \
    __builtin_amdgcn_sched_barrier(0);                                        \
    G2_LOADB(SET, k0 + 96);                                                   \
    __builtin_amdgcn_sched_barrier(0);                                        \
    G2_MFMA(CUR);                                                             \
    asm volatile("s_waitcnt vmcnt(2) lgkmcnt(0)" ::: "memory");               \
    __builtin_amdgcn_sched_barrier(0);                                        \
    __builtin_amdgcn_s_barrier();                                             \
    __builtin_amdgcn_sched_barrier(0);                                        \
    k0 += 32; }

  int k0 = 0;
  while (k0 < 384) {              // t = 0..11 (pairs)
    G2_STEP(0, 0);
    G2_STEP(1, 1);
  }
  G2_STEP(0, 0);                  // t = 12: loads B(15) at k0+96 = 480
  // t = 13 (CUR = 1): write B(14) from set1, stage A(14)
  G2_WRITEB(0, 1);
  __builtin_amdgcn_sched_barrier(0);
  gload16(asrc0 + 448, &As[0][arow0]);
  gload16(asrc1 + 448, &As[0][arow1]);
  __builtin_amdgcn_sched_barrier(0);
  G2_MFMA(1);
  asm volatile("s_waitcnt vmcnt(0) lgkmcnt(0)" ::: "memory");
  __builtin_amdgcn_sched_barrier(0);
  __builtin_amdgcn_s_barrier();
  __builtin_amdgcn_sched_barrier(0);
  // t = 14 (CUR = 0): write B(15) from set0, stage A(15)
  G2_WRITEB(1, 0);
  __builtin_amdgcn_sched_barrier(0);
  gload16(asrc0 + 480, &As[1][arow0]);
  gload16(asrc1 + 480, &As[1][arow1]);
  __builtin_amdgcn_sched_barrier(0);
  G2_MFMA(0);
  asm volatile("s_waitcnt vmcnt(0) lgkmcnt(0)" ::: "memory");
  __builtin_amdgcn_sched_barrier(0);
  __builtin_amdgcn_s_barrier();
  __builtin_amdgcn_sched_barrier(0);
  // t = 15
  G2_MFMA(1);

#undef G2_STEP
#undef G2_MFMA
#undef G2_WRITEB
#undef G2_LOADB

  // epilogue: + b2 (k-chunk 0 only), scale, atomic scatter-add
  #pragma unroll
  for (int i = 0; i < 4; i++) {
    #pragma unroll
    for (int r = 0; r < 4; r++) {
      const int m = wm*64 + i*16 + quad*4 + r;
      if (m0 + m < nt) {
        const int slot = off + m0 + m;
        const int t    = etok[slot];
        const float s  = escale[slot];
        #pragma unroll
        for (int j = 0; j < 4; j++) {
          const int n = n0 + wn*64 + j*16 + lr;
          float v = acc[i][j][r];
          if (kc == 0) v += b2[e*HDIM + n];
          atomicAdd(&out[(size_t)t*HDIM + n], s * v);
        }
      }
    }
  }
}

extern "C" void kernel_launch(void* const* d_in, const int* in_sizes, int n_in,
                              void* d_out, int out_size, void* d_ws, size_t ws_size,
                              hipStream_t stream) {
  const float* hidden = (const float*)d_in[0];
  const int*   sel    = (const int*)d_in[1];
  const float* scal   = (const float*)d_in[2];
  const float* w1     = (const float*)d_in[3];
  const float* b1     = (const float*)d_in[4];
  const float* w2     = (const float*)d_in[5];
  const float* b2     = (const float*)d_in[6];
  float* out = (float*)d_out;

  char* ws = (char*)d_ws;
  int*    offsets = (int*)(ws + WB_OFFSETS);
  int*    etok    = (int*)(ws + WB_ETOK);
  float*  escale  = (float*)(ws + WB_ESCALE);
  bf16_t* act     = (bf16_t*)(ws + WB_ACT);
  bf16_t* hbf     = (bf16_t*)(ws + WB_H);

  hipMemsetAsync(d_out, 0, (size_t)out_size * sizeof(float), stream);

  route_all<<<1, 256, 0, stream>>>(sel, scal, offsets, etok, escale);
  convert_h<<<(int)(H_ELEMS/8/256), 256, 0, stream>>>(hidden, hbf);

  // gemm1: x = n-tile (32), y = expert (8), z = m-tile (BM=256; ~1 live/expert).
  gemm1_v9<<<dim3(FDIM/64, NEXP, NENT/256), 512, 0, stream>>>(hbf, w1, b1, offsets, etok, act);
  // gemm2: x = n-tile(8) x splitK(4), y = expert, z = m-tile (BM=256).
  gemm2_v9<<<dim3((HDIM/128)*4, NEXP, NENT/256), 512, 0, stream>>>(act, w2, b2, offsets, etok, escale, out);
}

// Round 5
// 358.281 us; speedup vs baseline: 1.0609x; 1.0609x over previous
//
#include <hip/hip_runtime.h>
#include <hip/hip_bf16.h>
#include <cstdint>
#include <cstddef>

// Problem constants (fixed by the reference)
#define TDIM 1024
#define HDIM 1024
#define FDIM 2048
#define NEXP 8
#define NENT 2048   // T * K

typedef __bf16 bf16_t;
typedef __bf16 bf16x4 __attribute__((ext_vector_type(4)));
typedef __bf16 bf16x8 __attribute__((ext_vector_type(8)));
typedef float  f32x4  __attribute__((ext_vector_type(4)));

#define H_ELEMS  ((size_t)TDIM*HDIM)            // 1048576
#define W1_ELEMS ((size_t)NEXP*2*FDIM*HDIM)     // 33554432
#define W2_ELEMS ((size_t)NEXP*HDIM*FDIM)       // 16777216

// ---------------- workspace layout (bytes) ----------------
#define WB_OFFSETS 0                                   // int[16]
#define WB_ETOK    64
#define WB_ESCALE  (WB_ETOK + NENT*4)
#define WB_ACT     16512                               // bf16[NENT][FDIM] = 8 MB
#define WB_H       (WB_ACT + (size_t)NENT*FDIM*2)      // bf16[T][H] = 2 MB
#define WB_W2BF    (WB_H + H_ELEMS*2)                  // bf16 w2 = 32 MB
#define WB_W1BF    (WB_W2BF + W2_ELEMS*2)              // bf16 w1 = 64 MB
#define WB_NEED    (WB_W1BF + W1_ELEMS*2)              // ~106 MB total

__device__ __forceinline__ void gload16(const void* g, void* l) {
  __builtin_amdgcn_global_load_lds((const __attribute__((address_space(1))) void*)g,
                                   (__attribute__((address_space(3))) void*)l, 16, 0, 0);
}

__device__ __forceinline__ bf16x8 cvt8(const float4 a, const float4 b) {
  bf16x8 o;
  o[0]=(bf16_t)a.x; o[1]=(bf16_t)a.y; o[2]=(bf16_t)a.z; o[3]=(bf16_t)a.w;
  o[4]=(bf16_t)b.x; o[5]=(bf16_t)b.y; o[6]=(bf16_t)b.z; o[7]=(bf16_t)b.w;
  return o;
}

// 3-bit bank swizzle: seg position = seg ^ (row&3) ^ ((row>>2)&3).
__device__ __forceinline__ int segswz(int seg, int row) {
  return seg ^ (row & 3) ^ ((row >> 2) & 3);
}

// ---------------- routing (single block, one launch) ----------------
__global__ void route_all(const int* __restrict__ sel, const float* __restrict__ scal,
                          int* __restrict__ offsets, int* __restrict__ etok,
                          float* __restrict__ escale) {
  __shared__ int cnt[NEXP], cnt2[NEXP], offs[NEXP+1];
  const int t = threadIdx.x;    // 256 threads, 8 entries each
  if (t < NEXP) { cnt[t] = 0; cnt2[t] = 0; }
  __syncthreads();
  int e8[8];
  #pragma unroll
  for (int q = 0; q < 8; q++) {
    int i = t*8 + q;
    e8[q] = sel[i];
    atomicAdd(&cnt[e8[q]], 1);
  }
  __syncthreads();
  if (t == 0) {
    int s = 0;
    for (int e = 0; e < NEXP; e++) { offs[e] = s; offsets[e] = s; s += cnt[e]; }
    offs[NEXP] = s; offsets[NEXP] = s;
  }
  __syncthreads();
  #pragma unroll
  for (int q = 0; q < 8; q++) {
    int i = t*8 + q;
    int e = e8[q];
    int pos = offs[e] + atomicAdd(&cnt2[e], 1);
    etok[pos]   = i >> 1;       // TOPK == 2
    escale[pos] = scal[i];
  }
}

// ---------------- fp32 -> bf16 streaming convert (hidden AND weights) ----
// Pure streamer: 8 elems/thread, coalesced float4 in / bf16x8 out. This is
// the kernel class that hits ~6 TB/s (m13) — it moves the weight bytes at
// streaming rate instead of the ~1 TB/s the latency-bound GEMM fetch gets.
__global__ void convert_h(const float* __restrict__ h, bf16_t* __restrict__ hbf) {
  size_t idx = ((size_t)blockIdx.x*256 + threadIdx.x) * 8;
  float4 v0 = ((const float4*)(h + idx))[0];
  float4 v1 = ((const float4*)(h + idx))[1];
  *(bf16x8*)(hbf + idx) = cvt8(v0, v1);
}

// ======== v10: bf16 weights, pure global_load_lds GEMMs ========
// Empirical law rounds 0-4: dur_gemm ~ FETCH_SIZE / 1 TB/s (latency-bound
// weight fetch). Pre-converting weights to bf16 (a) halves the weight bytes,
// (b) leaves them L3-resident for the GEMMs, (c) lets B go through
// global_load_lds with pre-swizzled source (m173) exactly like A — no reg
// prefetch, no cvt8, no ds_write in the K-loop.
// Per K-iter per thread: 2 A-gload16 + 2 B-gload16. Per wave: 8 ds_read_b128
// + 16 MFMA. Double-buffered LDS, 1 barrier/iter, vmcnt(0) drain (schedule
// proved non-critical in rounds 1-3).

// GEMM1: act = silu(x@w1g^T + b1g) * (x@w1l^T + b1l)   [BM=128, BN=64x2]
__global__ __launch_bounds__(256, 3) void gemm1_v10(
    const bf16_t* __restrict__ hbf, const bf16_t* __restrict__ w1bf,
    const float* __restrict__ b1, const int* __restrict__ offsets,
    const int* __restrict__ etok, bf16_t* __restrict__ act)
{
  const int e   = blockIdx.y;
  const int off = offsets[e];
  const int nt  = offsets[e+1] - off;
  const int m0  = blockIdx.z * 128;
  if (m0 >= nt) return;
  const int n0  = blockIdx.x * 64;

  __shared__ __align__(16) bf16_t As[2][128*32];   // 16 KB
  __shared__ __align__(16) bf16_t Bg[2][64*32];    //  8 KB
  __shared__ __align__(16) bf16_t Bl[2][64*32];    //  8 KB

  const int tid  = threadIdx.x;
  const int w    = tid >> 6, lane = tid & 63;
  const int quad = lane >> 4, lr = lane & 15;
  const int wm   = w >> 1,  wn = w & 1;

  // ---- A staging: wave w, inst i covers LDS rows [i*64 + w*16, +16) ----
  const bf16_t* asrc0; const bf16_t* asrc1;
  int arow0, arow1;
  {
    const int r0 = 0*64 + w*16 + (lane >> 2);
    const int r1 = 1*64 + w*16 + (lane >> 2);
    const int s0 = segswz(lane & 3, r0);
    const int s1 = segswz(lane & 3, r1);
    int e0 = m0 + r0; if (e0 > nt-1) e0 = nt-1;   // clamp; masked in epilogue
    int e1 = m0 + r1; if (e1 > nt-1) e1 = nt-1;
    asrc0 = hbf + (size_t)etok[off + e0]*HDIM + s0*8;
    asrc1 = hbf + (size_t)etok[off + e1]*HDIM + s1*8;
    arow0 = (0*64 + w*16)*32;                     // + lane*16B implicit
    arow1 = (1*64 + w*16)*32;
  }

  // ---- B staging: wave w covers rows [w*16, +16) of gate AND lin ----
  const bf16_t* gsrc; const bf16_t* lsrc;
  int bdst;
  {
    const int brow = w*16 + (lane >> 2);
    const int bseg = segswz(lane & 3, brow);
    gsrc = w1bf + ((size_t)e*2*FDIM + (size_t)(n0 + brow))*HDIM + bseg*8;
    lsrc = gsrc + (size_t)FDIM*HDIM;
    bdst = (w*16)*32;                             // wave-uniform base
  }

  // ---- loop-invariant fragment LDS offsets ----
  int aoff[4], boff[2];
  #pragma unroll
  for (int i = 0; i < 4; i++) {
    const int r = wm*64 + i*16 + lr;
    aoff[i] = r*32 + (segswz(quad, r) << 3);
  }
  #pragma unroll
  for (int j = 0; j < 2; j++) {
    const int r = wn*32 + j*16 + lr;
    boff[j] = r*32 + (segswz(quad, r) << 3);
  }

  f32x4 accg[4][2] = {}, accl[4][2] = {};

#define G1_STAGE(K0, NXT)                                                     \
  { gload16(asrc0 + (K0), &As[NXT][arow0]);                                   \
    gload16(asrc1 + (K0), &As[NXT][arow1]);                                   \
    gload16(gsrc  + (K0), &Bg[NXT][bdst]);                                    \
    gload16(lsrc  + (K0), &Bl[NXT][bdst]); }

#define G1_MFMA(CUR)                                                          \
  { bf16x8 af[4], gf[2], lf[2];                                               \
    _Pragma("unroll")                                                         \
    for (int i = 0; i < 4; i++) af[i] = *(const bf16x8*)&As[CUR][aoff[i]];    \
    _Pragma("unroll")                                                         \
    for (int j = 0; j < 2; j++) {                                             \
      gf[j] = *(const bf16x8*)&Bg[CUR][boff[j]];                              \
      lf[j] = *(const bf16x8*)&Bl[CUR][boff[j]];                              \
    }                                                                         \
    _Pragma("unroll")                                                         \
    for (int i = 0; i < 4; i++)                                               \
      _Pragma("unroll")                                                       \
      for (int j = 0; j < 2; j++) {                                           \
        accg[i][j] = __builtin_amdgcn_mfma_f32_16x16x32_bf16(af[i], gf[j], accg[i][j], 0, 0, 0); \
        accl[i][j] = __builtin_amdgcn_mfma_f32_16x16x32_bf16(af[i], lf[j], accl[i][j], 0, 0, 0); \
      } }

#define G1_STEP(CUR)                                                          \
  { G1_STAGE(k0 + 32, (CUR)^1);                                               \
    __builtin_amdgcn_sched_barrier(0);                                        \
    G1_MFMA(CUR);                                                             \
    asm volatile("s_waitcnt vmcnt(0)" ::: "memory");                          \
    __builtin_amdgcn_sched_barrier(0);                                        \
    __builtin_amdgcn_s_barrier();                                             \
    __builtin_amdgcn_sched_barrier(0);                                        \
    k0 += 32; }

  // prologue: stage tile 0
  G1_STAGE(0, 0);
  asm volatile("s_waitcnt vmcnt(0)" ::: "memory");
  __builtin_amdgcn_sched_barrier(0);
  __builtin_amdgcn_s_barrier();
  __builtin_amdgcn_sched_barrier(0);

  int k0 = 0;
  while (k0 < 960) {              // t = 0..29 in pairs
    G1_STEP(0);
    G1_STEP(1);
  }
  G1_STEP(0);                     // t = 30: stages 992 -> buf1, computes buf0
  G1_MFMA(1);                     // t = 31

#undef G1_STEP
#undef G1_MFMA
#undef G1_STAGE

  // epilogue: bias + silu(gate)*lin -> act (bf16)
  #pragma unroll
  for (int j = 0; j < 2; j++) {
    const int f = n0 + wn*32 + j*16 + lr;
    const float bg_ = b1[e*2*FDIM + f];
    const float bl_ = b1[e*2*FDIM + FDIM + f];
    #pragma unroll
    for (int i = 0; i < 4; i++) {
      #pragma unroll
      for (int r = 0; r < 4; r++) {
        const int m = wm*64 + i*16 + quad*4 + r;
        if (m0 + m < nt) {
          const float g = accg[i][j][r] + bg_;
          const float l = accl[i][j][r] + bl_;
          const float s = g / (1.f + __expf(-g)) * l;
          act[(size_t)(off + m0 + m)*FDIM + f] = (bf16_t)s;
        }
      }
    }
  }
}

// GEMM2: y = act @ w2^T + b2; out[token] += scale*y  [BM=128, BN=128, splitK x4]
__global__ __launch_bounds__(256, 3) void gemm2_v10(
    const bf16_t* __restrict__ act, const bf16_t* __restrict__ w2bf,
    const float* __restrict__ b2, const int* __restrict__ offsets,
    const int* __restrict__ etok, const float* __restrict__ escale,
    float* __restrict__ out)
{
  const int e   = blockIdx.y;
  const int off = offsets[e];
  const int nt  = offsets[e+1] - off;
  const int m0  = blockIdx.z * 128;
  if (m0 >= nt) return;
  const int n0  = (blockIdx.x >> 2) * 128;
  const int kc  = blockIdx.x & 3;
  const int kbeg = kc * (FDIM/4);          // 512-chunk, 16 iters

  __shared__ __align__(16) bf16_t As[2][128*32];   // 16 KB
  __shared__ __align__(16) bf16_t Bs[2][128*32];   // 16 KB

  const int tid  = threadIdx.x;
  const int w    = tid >> 6, lane = tid & 63;
  const int quad = lane >> 4, lr = lane & 15;
  const int wm   = w >> 1,  wn = w & 1;

  const bf16_t* asrc0; const bf16_t* asrc1;
  int arow0, arow1;
  {
    const int r0 = 0*64 + w*16 + (lane >> 2);
    const int r1 = 1*64 + w*16 + (lane >> 2);
    const int s0 = segswz(lane & 3, r0);
    const int s1 = segswz(lane & 3, r1);
    int e0 = m0 + r0; if (e0 > nt-1) e0 = nt-1;
    int e1 = m0 + r1; if (e1 > nt-1) e1 = nt-1;
    asrc0 = act + (size_t)(off + e0)*FDIM + kbeg + s0*8;
    asrc1 = act + (size_t)(off + e1)*FDIM + kbeg + s1*8;
    arow0 = (0*64 + w*16)*32;
    arow1 = (1*64 + w*16)*32;
  }

  // B staging: wave w covers rows [w*32, +32) via two instructions
  const bf16_t* bsrc0; const bf16_t* bsrc1;
  int bdst0, bdst1;
  {
    const int r0 = w*32 + (lane >> 2);
    const int r1 = w*32 + 16 + (lane >> 2);
    const int s0 = segswz(lane & 3, r0);
    const int s1 = segswz(lane & 3, r1);
    bsrc0 = w2bf + ((size_t)e*HDIM + (size_t)(n0 + r0))*FDIM + kbeg + s0*8;
    bsrc1 = w2bf + ((size_t)e*HDIM + (size_t)(n0 + r1))*FDIM + kbeg + s1*8;
    bdst0 = (w*32)*32;
    bdst1 = (w*32 + 16)*32;
  }

  int aoff[4], boff[4];
  #pragma unroll
  for (int i = 0; i < 4; i++) {
    const int r = wm*64 + i*16 + lr;
    aoff[i] = r*32 + (segswz(quad, r) << 3);
  }
  #pragma unroll
  for (int j = 0; j < 4; j++) {
    const int r = wn*64 + j*16 + lr;
    boff[j] = r*32 + (segswz(quad, r) << 3);
  }

  f32x4 acc[4][4] = {};

#define G2_STAGE(K0, NXT)                                                     \
  { gload16(asrc0 + (K0), &As[NXT][arow0]);                                   \
    gload16(asrc1 + (K0), &As[NXT][arow1]);                                   \
    gload16(bsrc0 + (K0), &Bs[NXT][bdst0]);                                   \
    gload16(bsrc1 + (K0), &Bs[NXT][bdst1]); }

#define G2_MFMA(CUR)                                                          \
  { bf16x8 af[4], bfr[4];                                                     \
    _Pragma("unroll")                                                         \
    for (int i = 0; i < 4; i++) af[i] = *(const bf16x8*)&As[CUR][aoff[i]];    \
    _Pragma("unroll")                                                         \
    for (int j = 0; j < 4; j++) bfr[j] = *(const bf16x8*)&Bs[CUR][boff[j]];   \
    _Pragma("unroll")                                                         \
    for (int i = 0; i < 4; i++)                                               \
      _Pragma("unroll")                                                       \
      for (int j = 0; j < 4; j++)                                             \
        acc[i][j] = __builtin_amdgcn_mfma_f32_16x16x32_bf16(af[i], bfr[j], acc[i][j], 0, 0, 0); }

#define G2_STEP(CUR)                                                          \
  { G2_STAGE(k0 + 32, (CUR)^1);                                               \
    __builtin_amdgcn_sched_barrier(0);                                        \
    G2_MFMA(CUR);                                                             \
    asm volatile("s_waitcnt vmcnt(0)" ::: "memory");                          \
    __builtin_amdgcn_sched_barrier(0);                                        \
    __builtin_amdgcn_s_barrier();                                             \
    __builtin_amdgcn_sched_barrier(0);                                        \
    k0 += 32; }

  G2_STAGE(0, 0);
  asm volatile("s_waitcnt vmcnt(0)" ::: "memory");
  __builtin_amdgcn_sched_barrier(0);
  __builtin_amdgcn_s_barrier();
  __builtin_amdgcn_sched_barrier(0);

  int k0 = 0;
  while (k0 < 448) {              // t = 0..13 in pairs
    G2_STEP(0);
    G2_STEP(1);
  }
  G2_STEP(0);                     // t = 14: stages 480 -> buf1, computes buf0
  G2_MFMA(1);                     // t = 15

#undef G2_STEP
#undef G2_MFMA
#undef G2_STAGE

  // epilogue: + b2 (k-chunk 0 only), scale, atomic scatter-add
  #pragma unroll
  for (int i = 0; i < 4; i++) {
    #pragma unroll
    for (int r = 0; r < 4; r++) {
      const int m = wm*64 + i*16 + quad*4 + r;
      if (m0 + m < nt) {
        const int slot = off + m0 + m;
        const int t    = etok[slot];
        const float s  = escale[slot];
        #pragma unroll
        for (int j = 0; j < 4; j++) {
          const int n = n0 + wn*64 + j*16 + lr;
          float v = acc[i][j][r];
          if (kc == 0) v += b2[e*HDIM + n];
          atomicAdd(&out[(size_t)t*HDIM + n], s * v);
        }
      }
    }
  }
}

// ======== fallback (round-3 fp32-weight kernels, used if ws too small) ====
__global__ __launch_bounds__(256, 3) void gemm1_v8(
    const bf16_t* __restrict__ hbf, const float* __restrict__ w1,
    const float* __restrict__ b1, const int* __restrict__ offsets,
    const int* __restrict__ etok, bf16_t* __restrict__ act)
{
  const int e   = blockIdx.y;
  const int off = offsets[e];
  const int nt  = offsets[e+1] - off;
  const int m0  = blockIdx.z * 128;
  if (m0 >= nt) return;
  const int n0  = blockIdx.x * 64;

  __shared__ __align__(16) bf16_t As[2][128*32];
  __shared__ __align__(16) bf16_t Bg[2][64*32];
  __shared__ __align__(16) bf16_t Bl[2][64*32];

  const int tid  = threadIdx.x;
  const int w    = tid >> 6, lane = tid & 63;
  const int quad = lane >> 4, lr = lane & 15;
  const int wm   = w >> 1,  wn = w & 1;

  const bf16_t* asrc0; const bf16_t* asrc1;
  int arow0, arow1;
  {
    const int r0 = 0*64 + w*16 + (lane >> 2);
    const int r1 = 1*64 + w*16 + (lane >> 2);
    const int s0 = segswz(lane & 3, r0);
    const int s1 = segswz(lane & 3, r1);
    int e0 = m0 + r0; if (e0 > nt-1) e0 = nt-1;
    int e1 = m0 + r1; if (e1 > nt-1) e1 = nt-1;
    asrc0 = hbf + (size_t)etok[off + e0]*HDIM + s0*8;
    asrc1 = hbf + (size_t)etok[off + e1]*HDIM + s1*8;
    arow0 = (0*64 + w*16)*32;
    arow1 = (1*64 + w*16)*32;
  }

  const int br = tid >> 2, bs = tid & 3;
  const float* gsrc = w1 + ((size_t)e*2*FDIM + (size_t)(n0 + br))*HDIM + bs*8;
  const float* lsrc = gsrc + (size_t)FDIM*HDIM;
  const int bofs = br*32 + (segswz(bs, br) << 3);

  int aoff[4], boff[2];
  #pragma unroll
  for (int i = 0; i < 4; i++) {
    const int r = wm*64 + i*16 + lr;
    aoff[i] = r*32 + (segswz(quad, r) << 3);
  }
  #pragma unroll
  for (int j = 0; j < 2; j++) {
    const int r = wn*32 + j*16 + lr;
    boff[j] = r*32 + (segswz(quad, r) << 3);
  }

  f32x4 accg[4][2] = {}, accl[4][2] = {};
  float4 g4[2][2], l4[2][2];

#define F1_LOADB(SET, K0)                                                     \
  { const float4* p_ = (const float4*)(gsrc + (K0));                          \
    g4[SET][0]=p_[0]; g4[SET][1]=p_[1];                                       \
    const float4* q_ = (const float4*)(lsrc + (K0));                          \
    l4[SET][0]=q_[0]; l4[SET][1]=q_[1]; }
#define F1_WRITEB(NXT, SET)                                                   \
  { *(bf16x8*)&Bg[NXT][bofs] = cvt8(g4[SET][0], g4[SET][1]);                  \
    *(bf16x8*)&Bl[NXT][bofs] = cvt8(l4[SET][0], l4[SET][1]); }
#define F1_MFMA(CUR)                                                          \
  { bf16x8 af[4], gf[2], lf[2];                                               \
    _Pragma("unroll")                                                         \
    for (int i = 0; i < 4; i++) af[i] = *(const bf16x8*)&As[CUR][aoff[i]];    \
    _Pragma("unroll")                                                         \
    for (int j = 0; j < 2; j++) {                                             \
      gf[j] = *(const bf16x8*)&Bg[CUR][boff[j]];                              \
      lf[j] = *(const bf16x8*)&Bl[CUR][boff[j]];                              \
    }                                                                         \
    _Pragma("unroll")                                                         \
    for (int i = 0; i < 4; i++)                                               \
      _Pragma("unroll")                                                       \
      for (int j = 0; j < 2; j++) {                                           \
        accg[i][j] = __builtin_amdgcn_mfma_f32_16x16x32_bf16(af[i], gf[j], accg[i][j], 0, 0, 0); \
        accl[i][j] = __builtin_amdgcn_mfma_f32_16x16x32_bf16(af[i], lf[j], accl[i][j], 0, 0, 0); \
      } }

  F1_LOADB(0, 0);
  __builtin_amdgcn_sched_barrier(0);
  gload16(asrc0 + 0, &As[0][arow0]);
  gload16(asrc1 + 0, &As[0][arow1]);
  __builtin_amdgcn_sched_barrier(0);
  F1_WRITEB(0, 0);
  F1_LOADB(0, 32);
  F1_LOADB(1, 64);
  asm volatile("s_waitcnt vmcnt(8) lgkmcnt(0)" ::: "memory");
  __builtin_amdgcn_sched_barrier(0);
  __builtin_amdgcn_s_barrier();
  __builtin_amdgcn_sched_barrier(0);

#define F1_STEP(CUR, SET)                                                     \
  { F1_WRITEB((CUR)^1, SET);                                                  \
    __builtin_amdgcn_sched_barrier(0);                                        \
    gload16(asrc0 + k0 + 32, &As[(CUR)^1][arow0]);                            \
    gload16(asrc1 + k0 + 32, &As[(CUR)^1][arow1]);                            \
    __builtin_amdgcn_sched_barrier(0);                                        \
    F1_LOADB(SET, k0 + 96);                                                   \
    __builtin_amdgcn_sched_barrier(0);                                        \
    F1_MFMA(CUR);                                                             \
    asm volatile("s_waitcnt vmcnt(4) lgkmcnt(0)" ::: "memory");               \
    __builtin_amdgcn_sched_barrier(0);                                        \
    __builtin_amdgcn_s_barrier();                                             \
    __builtin_amdgcn_sched_barrier(0);                                        \
    k0 += 32; }

  int k0 = 0;
  while (k0 < 896) { F1_STEP(0, 0); F1_STEP(1, 1); }
  F1_STEP(0, 0);
  F1_WRITEB(0, 1);
  __builtin_amdgcn_sched_barrier(0);
  gload16(asrc0 + 960, &As[0][arow0]);
  gload16(asrc1 + 960, &As[0][arow1]);
  __builtin_amdgcn_sched_barrier(0);
  F1_MFMA(1);
  asm volatile("s_waitcnt vmcnt(0) lgkmcnt(0)" ::: "memory");
  __builtin_amdgcn_sched_barrier(0);
  __builtin_amdgcn_s_barrier();
  __builtin_amdgcn_sched_barrier(0);
  F1_WRITEB(1, 0);
  __builtin_amdgcn_sched_barrier(0);
  gload16(asrc0 + 992, &As[1][arow0]);
  gload16(asrc1 + 992, &As[1][arow1]);
  __builtin_amdgcn_sched_barrier(0);
  F1_MFMA(0);
  asm volatile("s_waitcnt vmcnt(0) lgkmcnt(0)" ::: "memory");
  __builtin_amdgcn_sched_barrier(0);
  __builtin_amdgcn_s_barrier();
  __builtin_amdgcn_sched_barrier(0);
  F1_MFMA(1);

#undef F1_STEP
#undef F1_MFMA
#undef F1_WRITEB
#undef F1_LOADB

  #pragma unroll
  for (int j = 0; j < 2; j++) {
    const int f = n0 + wn*32 + j*16 + lr;
    const float bg_ = b1[e*2*FDIM + f];
    const float bl_ = b1[e*2*FDIM + FDIM + f];
    #pragma unroll
    for (int i = 0; i < 4; i++) {
      #pragma unroll
      for (int r = 0; r < 4; r++) {
        const int m = wm*64 + i*16 + quad*4 + r;
        if (m0 + m < nt) {
          const float g = accg[i][j][r] + bg_;
          const float l = accl[i][j][r] + bl_;
          const float s = g / (1.f + __expf(-g)) * l;
          act[(size_t)(off + m0 + m)*FDIM + f] = (bf16_t)s;
        }
      }
    }
  }
}

__global__ __launch_bounds__(256, 3) void gemm2_v8(
    const bf16_t* __restrict__ act, const float* __restrict__ w2,
    const float* __restrict__ b2, const int* __restrict__ offsets,
    const int* __restrict__ etok, const float* __restrict__ escale,
    float* __restrict__ out)
{
  const int e   = blockIdx.y;
  const int off = offsets[e];
  const int nt  = offsets[e+1] - off;
  const int m0  = blockIdx.z * 128;
  if (m0 >= nt) return;
  const int n0  = (blockIdx.x >> 2) * 128;
  const int kc  = blockIdx.x & 3;
  const int kbeg = kc * (FDIM/4);

  __shared__ __align__(16) bf16_t As[2][128*32];
  __shared__ __align__(16) bf16_t Bs[2][128*32];

  const int tid  = threadIdx.x;
  const int w    = tid >> 6, lane = tid & 63;
  const int quad = lane >> 4, lr = lane & 15;
  const int wm   = w >> 1,  wn = w & 1;

  const bf16_t* asrc0; const bf16_t* asrc1;
  int arow0, arow1;
  {
    const int r0 = 0*64 + w*16 + (lane >> 2);
    const int r1 = 1*64 + w*16 + (lane >> 2);
    const int s0 = segswz(lane & 3, r0);
    const int s1 = segswz(lane & 3, r1);
    int e0 = m0 + r0; if (e0 > nt-1) e0 = nt-1;
    int e1 = m0 + r1; if (e1 > nt-1) e1 = nt-1;
    asrc0 = act + (size_t)(off + e0)*FDIM + kbeg + s0*8;
    asrc1 = act + (size_t)(off + e1)*FDIM + kbeg + s1*8;
    arow0 = (0*64 + w*16)*32;
    arow1 = (1*64 + w*16)*32;
  }

  const int br = tid >> 1, bc = tid & 1;
  const float* bsrc = w2 + ((size_t)e*HDIM + (size_t)(n0 + br))*FDIM + kbeg + bc*16;
  const int bofs0 = br*32 + (segswz(2*bc,   br) << 3);
  const int bofs1 = br*32 + (segswz(2*bc+1, br) << 3);

  int aoff[4], boff[4];
  #pragma unroll
  for (int i = 0; i < 4; i++) {
    const int r = wm*64 + i*16 + lr;
    aoff[i] = r*32 + (segswz(quad, r) << 3);
  }
  #pragma unroll
  for (int j = 0; j < 4; j++) {
    const int r = wn*64 + j*16 + lr;
    boff[j] = r*32 + (segswz(quad, r) << 3);
  }

  f32x4 acc[4][4] = {};
  float4 b4[2][4];

#define F2_LOADB(SET, K0)                                                     \
  { const float4* p_ = (const float4*)(bsrc + (K0));                          \
    b4[SET][0]=p_[0]; b4[SET][1]=p_[1]; b4[SET][2]=p_[2]; b4[SET][3]=p_[3]; }
#define F2_WRITEB(NXT, SET)                                                   \
  { *(bf16x8*)&Bs[NXT][bofs0] = cvt8(b4[SET][0], b4[SET][1]);                 \
    *(bf16x8*)&Bs[NXT][bofs1] = cvt8(b4[SET][2], b4[SET][3]); }
#define F2_MFMA(CUR)                                                          \
  { bf16x8 af[4], bfr[4];                                                     \
    _Pragma("unroll")                                                         \
    for (int i = 0; i < 4; i++) af[i] = *(const bf16x8*)&As[CUR][aoff[i]];    \
    _Pragma("unroll")                                                         \
    for (int j = 0; j < 4; j++) bfr[j] = *(const bf16x8*)&Bs[CUR][boff[j]];   \
    _Pragma("unroll")                                                         \
    for (int i = 0; i < 4; i++)                                               \
      _Pragma("unroll")                                                       \
      for (int j = 0; j < 4; j++)                                             \
        acc[i][j] = __builtin_amdgcn_mfma_f32_16x16x32_bf16(af[i], bfr[j], acc[i][j], 0, 0, 0); }

  F2_LOADB(0, 0);
  __builtin_amdgcn_sched_barrier(0);
  gload16(asrc0 + 0, &As[0][arow0]);
  gload16(asrc1 + 0, &As[0][arow1]);
  __builtin_amdgcn_sched_barrier(0);
  F2_WRITEB(0, 0);
  F2_LOADB(0, 32);
  F2_LOADB(1, 64);
  asm volatile("s_waitcnt vmcnt(8) lgkmcnt(0)" ::: "memory");
  __builtin_amdgcn_sched_barrier(0);
  __builtin_amdgcn_s_barrier();
  __builtin_amdgcn_sched_barrier(0);

#define F2_STEP(CUR, SET)                                                     \
  { F2_WRITEB((CUR)^1, SET);                                                  \
    __builtin_amdgcn_sched_barrier(0);                                        \
    gload16(asrc0 + k0 + 32, &As[(CUR)^1][arow0]);                            \
    gload16(asrc1 + k0 + 32, &As[(CUR)^1][arow1]);                            \
    __builtin_amdgcn_sched_barrier(0);                                        \
    F2_LOADB(SET, k0 + 96);                                                   \
    __builtin_amdgcn_sched_barrier(0);                                        \
    F2_MFMA(CUR);                                                             \
    asm volatile("s_waitcnt vmcnt(4) lgkmcnt(0)" ::: "memory");               \
    __builtin_amdgcn_sched_barrier(0);                                        \
    __builtin_amdgcn_s_barrier();                                             \
    __builtin_amdgcn_sched_barrier(0);                                        \
    k0 += 32; }

  int k0 = 0;
  while (k0 < 384) { F2_STEP(0, 0); F2_STEP(1, 1); }
  F2_STEP(0, 0);
  F2_WRITEB(0, 1);
  __builtin_amdgcn_sched_barrier(0);
  gload16(asrc0 + 448, &As[0][arow0]);
  gload16(asrc1 + 448, &As[0][arow1]);
  __builtin_amdgcn_sched_barrier(0);
  F2_MFMA(1);
  asm volatile("s_waitcnt vmcnt(0) lgkmcnt(0)" ::: "memory");
  __builtin_amdgcn_sched_barrier(0);
  __builtin_amdgcn_s_barrier();
  __builtin_amdgcn_sched_barrier(0);
  F2_WRITEB(1, 0);
  __builtin_amdgcn_sched_barrier(0);
  gload16(asrc0 + 480, &As[1][arow0]);
  gload16(asrc1 + 480, &As[1][arow1]);
  __builtin_amdgcn_sched_barrier(0);
  F2_MFMA(0);
  asm volatile("s_waitcnt vmcnt(0) lgkmcnt(0)" ::: "memory");
  __builtin_amdgcn_sched_barrier(0);
  __builtin_amdgcn_s_barrier();
  __builtin_amdgcn_sched_barrier(0);
  F2_MFMA(1);

#undef F2_STEP
#undef F2_MFMA
#undef F2_WRITEB
#undef F2_LOADB

  #pragma unroll
  for (int i = 0; i < 4; i++) {
    #pragma unroll
    for (int r = 0; r < 4; r++) {
      const int m = wm*64 + i*16 + quad*4 + r;
      if (m0 + m < nt) {
        const int slot = off + m0 + m;
        const int t    = etok[slot];
        const float s  = escale[slot];
        #pragma unroll
        for (int j = 0; j < 4; j++) {
          const int n = n0 + wn*64 + j*16 + lr;
          float v = acc[i][j][r];
          if (kc == 0) v += b2[e*HDIM + n];
          atomicAdd(&out[(size_t)t*HDIM + n], s * v);
        }
      }
    }
  }
}

extern "C" void kernel_launch(void* const* d_in, const int* in_sizes, int n_in,
                              void* d_out, int out_size, void* d_ws, size_t ws_size,
                              hipStream_t stream) {
  const float* hidden = (const float*)d_in[0];
  const int*   sel    = (const int*)d_in[1];
  const float* scal   = (const float*)d_in[2];
  const float* w1     = (const float*)d_in[3];
  const float* b1     = (const float*)d_in[4];
  const float* w2     = (const float*)d_in[5];
  const float* b2     = (const float*)d_in[6];
  float* out = (float*)d_out;

  char* ws = (char*)d_ws;
  int*    offsets = (int*)(ws + WB_OFFSETS);
  int*    etok    = (int*)(ws + WB_ETOK);
  float*  escale  = (float*)(ws + WB_ESCALE);
  bf16_t* act     = (bf16_t*)(ws + WB_ACT);
  bf16_t* hbf     = (bf16_t*)(ws + WB_H);
  bf16_t* w2bf    = (bf16_t*)(ws + WB_W2BF);
  bf16_t* w1bf    = (bf16_t*)(ws + WB_W1BF);

  hipMemsetAsync(d_out, 0, (size_t)out_size * sizeof(float), stream);

  route_all<<<1, 256, 0, stream>>>(sel, scal, offsets, etok, escale);
  convert_h<<<(int)(H_ELEMS/8/256), 256, 0, stream>>>(hidden, hbf);

  if (ws_size >= WB_NEED) {
    // bf16-weight path: streaming converters (w2 first so w1bf is freshest
    // in L3 when gemm1 runs), then pure-gload16 GEMMs.
    convert_h<<<(int)(W2_ELEMS/8/256), 256, 0, stream>>>(w2, w2bf);
    convert_h<<<(int)(W1_ELEMS/8/256), 256, 0, stream>>>(w1, w1bf);
    gemm1_v10<<<dim3(FDIM/64, NEXP, NENT/128), 256, 0, stream>>>(hbf, w1bf, b1, offsets, etok, act);
    gemm2_v10<<<dim3((HDIM/128)*4, NEXP, NENT/128), 256, 0, stream>>>(act, w2bf, b2, offsets, etok, escale, out);
  } else {
    // fallback: round-3 fp32-weight kernels
    gemm1_v8<<<dim3(FDIM/64, NEXP, NENT/128), 256, 0, stream>>>(hbf, w1, b1, offsets, etok, act);
    gemm2_v8<<<dim3((HDIM/128)*4, NEXP, NENT/128), 256, 0, stream>>>(act, w2, b2, offsets, etok, escale, out);
  }
}

// Round 6
// 356.940 us; speedup vs baseline: 1.0649x; 1.0038x over previous
//
#include <hip/hip_runtime.h>
#include <hip/hip_bf16.h>
#include <cstdint>
#include <cstddef>

// Problem constants (fixed by the reference)
#define TDIM 1024
#define HDIM 1024
#define FDIM 2048
#define NEXP 8
#define NENT 2048   // T * K

typedef __bf16 bf16_t;
typedef __bf16 bf16x4 __attribute__((ext_vector_type(4)));
typedef __bf16 bf16x8 __attribute__((ext_vector_type(8)));
typedef float  f32x4  __attribute__((ext_vector_type(4)));

#define H_ELEMS  ((size_t)TDIM*HDIM)            // 1048576
#define W1_ELEMS ((size_t)NEXP*2*FDIM*HDIM)     // 33554432
#define W2_ELEMS ((size_t)NEXP*HDIM*FDIM)       // 16777216

// ---------------- workspace layout (bytes) ----------------
#define WB_OFFSETS 0                                   // int[16]
#define WB_ETOK    64
#define WB_ESCALE  (WB_ETOK + NENT*4)
#define WB_ACT     16512                               // bf16[NENT][FDIM] = 8 MB
#define WB_H       (WB_ACT + (size_t)NENT*FDIM*2)      // bf16[T][H] = 2 MB
#define WB_W2BF    (WB_H + H_ELEMS*2)                  // bf16 w2 = 32 MB
#define WB_W1BF    (WB_W2BF + W2_ELEMS*2)              // bf16 w1 = 64 MB
#define WB_NEED    (WB_W1BF + W1_ELEMS*2)              // ~106 MB total

__device__ __forceinline__ void gload16(const void* g, void* l) {
  __builtin_amdgcn_global_load_lds((const __attribute__((address_space(1))) void*)g,
                                   (__attribute__((address_space(3))) void*)l, 16, 0, 0);
}

__device__ __forceinline__ bf16x8 cvt8(const float4 a, const float4 b) {
  bf16x8 o;
  o[0]=(bf16_t)a.x; o[1]=(bf16_t)a.y; o[2]=(bf16_t)a.z; o[3]=(bf16_t)a.w;
  o[4]=(bf16_t)b.x; o[5]=(bf16_t)b.y; o[6]=(bf16_t)b.z; o[7]=(bf16_t)b.w;
  return o;
}

// 3-bit bank swizzle: seg position = seg ^ (row&3) ^ ((row>>2)&3).
__device__ __forceinline__ int segswz(int seg, int row) {
  return seg ^ (row & 3) ^ ((row >> 2) & 3);
}

// ---------------- routing (single block, one launch) ----------------
__global__ void route_all(const int* __restrict__ sel, const float* __restrict__ scal,
                          int* __restrict__ offsets, int* __restrict__ etok,
                          float* __restrict__ escale) {
  __shared__ int cnt[NEXP], cnt2[NEXP], offs[NEXP+1];
  const int t = threadIdx.x;    // 256 threads, 8 entries each
  if (t < NEXP) { cnt[t] = 0; cnt2[t] = 0; }
  __syncthreads();
  int e8[8];
  #pragma unroll
  for (int q = 0; q < 8; q++) {
    int i = t*8 + q;
    e8[q] = sel[i];
    atomicAdd(&cnt[e8[q]], 1);
  }
  __syncthreads();
  if (t == 0) {
    int s = 0;
    for (int e = 0; e < NEXP; e++) { offs[e] = s; offsets[e] = s; s += cnt[e]; }
    offs[NEXP] = s; offsets[NEXP] = s;
  }
  __syncthreads();
  #pragma unroll
  for (int q = 0; q < 8; q++) {
    int i = t*8 + q;
    int e = e8[q];
    int pos = offs[e] + atomicAdd(&cnt2[e], 1);
    etok[pos]   = i >> 1;       // TOPK == 2
    escale[pos] = scal[i];
  }
}

// ---------------- fp32 -> bf16 streaming convert ----------------
__global__ void convert_h(const float* __restrict__ h, bf16_t* __restrict__ hbf) {
  size_t idx = ((size_t)blockIdx.x*256 + threadIdx.x) * 8;
  float4 v0 = ((const float4*)(h + idx))[0];
  float4 v1 = ((const float4*)(h + idx))[1];
  *(bf16x8*)(hbf + idx) = cvt8(v0, v1);
}

// ======== v11: depth-2 LDS staging pipeline (triple buffer) ========
// Rounds 0-5 invariant: GEMM fetch-rate stuck ~1 TB/s while streaming fills
// hit 6.8 TB/s. Cause: every prior schedule DRAINED the LDS-staging gloads
// each iteration (duty cycle of outstanding L2-misses ~35%). v11: 3 LDS
// buffers; iter t issues STAGE(t+2), computes tile t, waits vmcnt(4) so
// stage(t+1) is complete while stage(t+2)'s 4 loads remain in flight ACROSS
// the barrier. Each stage gets ~2 iterations to cover the ~600-900 cyc
// L3/HBM latency; the miss path stays occupied continuously.

// GEMM1: act = silu(x@w1g^T + b1g) * (x@w1l^T + b1l)   [BM=128, BN=64x2]
__global__ __launch_bounds__(256, 3) void gemm1_v11(
    const bf16_t* __restrict__ hbf, const bf16_t* __restrict__ w1bf,
    const float* __restrict__ b1, const int* __restrict__ offsets,
    const int* __restrict__ etok, bf16_t* __restrict__ act)
{
  const int e   = blockIdx.y;
  const int off = offsets[e];
  const int nt  = offsets[e+1] - off;
  const int m0  = blockIdx.z * 128;
  if (m0 >= nt) return;
  const int n0  = blockIdx.x * 64;

  __shared__ __align__(16) bf16_t As[3][128*32];   // 24 KB
  __shared__ __align__(16) bf16_t Bg[3][64*32];    // 12 KB
  __shared__ __align__(16) bf16_t Bl[3][64*32];    // 12 KB

  const int tid  = threadIdx.x;
  const int w    = tid >> 6, lane = tid & 63;
  const int quad = lane >> 4, lr = lane & 15;
  const int wm   = w >> 1,  wn = w & 1;

  // ---- A staging: wave w, inst i covers LDS rows [i*64 + w*16, +16) ----
  const bf16_t* asrc0; const bf16_t* asrc1;
  int arow0, arow1;
  {
    const int r0 = 0*64 + w*16 + (lane >> 2);
    const int r1 = 1*64 + w*16 + (lane >> 2);
    const int s0 = segswz(lane & 3, r0);
    const int s1 = segswz(lane & 3, r1);
    int e0 = m0 + r0; if (e0 > nt-1) e0 = nt-1;   // clamp; masked in epilogue
    int e1 = m0 + r1; if (e1 > nt-1) e1 = nt-1;
    asrc0 = hbf + (size_t)etok[off + e0]*HDIM + s0*8;
    asrc1 = hbf + (size_t)etok[off + e1]*HDIM + s1*8;
    arow0 = (0*64 + w*16)*32;                     // + lane*16B implicit
    arow1 = (1*64 + w*16)*32;
  }

  // ---- B staging: wave w covers rows [w*16, +16) of gate AND lin ----
  const bf16_t* gsrc; const bf16_t* lsrc;
  int bdst;
  {
    const int brow = w*16 + (lane >> 2);
    const int bseg = segswz(lane & 3, brow);
    gsrc = w1bf + ((size_t)e*2*FDIM + (size_t)(n0 + brow))*HDIM + bseg*8;
    lsrc = gsrc + (size_t)FDIM*HDIM;
    bdst = (w*16)*32;                             // wave-uniform base
  }

  // ---- loop-invariant fragment LDS offsets ----
  int aoff[4], boff[2];
  #pragma unroll
  for (int i = 0; i < 4; i++) {
    const int r = wm*64 + i*16 + lr;
    aoff[i] = r*32 + (segswz(quad, r) << 3);
  }
  #pragma unroll
  for (int j = 0; j < 2; j++) {
    const int r = wn*32 + j*16 + lr;
    boff[j] = r*32 + (segswz(quad, r) << 3);
  }

  f32x4 accg[4][2] = {}, accl[4][2] = {};

#define G1_STAGE(K0, NXT)                                                     \
  { gload16(asrc0 + (K0), &As[NXT][arow0]);                                   \
    gload16(asrc1 + (K0), &As[NXT][arow1]);                                   \
    gload16(gsrc  + (K0), &Bg[NXT][bdst]);                                    \
    gload16(lsrc  + (K0), &Bl[NXT][bdst]); }

#define G1_MFMA(CUR)                                                          \
  { bf16x8 af[4], gf[2], lf[2];                                               \
    _Pragma("unroll")                                                         \
    for (int i = 0; i < 4; i++) af[i] = *(const bf16x8*)&As[CUR][aoff[i]];    \
    _Pragma("unroll")                                                         \
    for (int j = 0; j < 2; j++) {                                             \
      gf[j] = *(const bf16x8*)&Bg[CUR][boff[j]];                              \
      lf[j] = *(const bf16x8*)&Bl[CUR][boff[j]];                              \
    }                                                                         \
    _Pragma("unroll")                                                         \
    for (int i = 0; i < 4; i++)                                               \
      _Pragma("unroll")                                                       \
      for (int j = 0; j < 2; j++) {                                           \
        accg[i][j] = __builtin_amdgcn_mfma_f32_16x16x32_bf16(af[i], gf[j], accg[i][j], 0, 0, 0); \
        accl[i][j] = __builtin_amdgcn_mfma_f32_16x16x32_bf16(af[i], lf[j], accl[i][j], 0, 0, 0); \
      } }

  // step at tile t (k0 = t*32): issue STAGE(t+2) -> buf NXT, compute buf CUR,
  // wait vmcnt(4): stage(t+1) complete, stage(t+2)'s 4 loads stay in flight.
#define G1_STEP(CUR, NXT)                                                     \
  { G1_STAGE(k0 + 64, NXT);                                                   \
    __builtin_amdgcn_sched_barrier(0);                                        \
    G1_MFMA(CUR);                                                             \
    asm volatile("s_waitcnt vmcnt(4)" ::: "memory");                          \
    __builtin_amdgcn_sched_barrier(0);                                        \
    __builtin_amdgcn_s_barrier();                                             \
    __builtin_amdgcn_sched_barrier(0);                                        \
    k0 += 32; }

  // prologue: stage tiles 0,1; wait tile0 complete (tile1 stays in flight)
  G1_STAGE(0, 0);
  G1_STAGE(32, 1);
  asm volatile("s_waitcnt vmcnt(4)" ::: "memory");
  __builtin_amdgcn_sched_barrier(0);
  __builtin_amdgcn_s_barrier();
  __builtin_amdgcn_sched_barrier(0);

  int k0 = 0;
  while (k0 < 960) {              // t = 0..29, unrolled x3 (10 passes)
    G1_STEP(0, 2);
    G1_STEP(1, 0);
    G1_STEP(2, 1);
  }
  // t = 30 (buf 0): stage(31) still in flight during MFMA, drain after
  G1_MFMA(0);
  asm volatile("s_waitcnt vmcnt(0)" ::: "memory");
  __builtin_amdgcn_sched_barrier(0);
  __builtin_amdgcn_s_barrier();
  __builtin_amdgcn_sched_barrier(0);
  G1_MFMA(1);                     // t = 31 (buf 1)

#undef G1_STEP
#undef G1_MFMA
#undef G1_STAGE

  // epilogue: bias + silu(gate)*lin -> act (bf16)
  #pragma unroll
  for (int j = 0; j < 2; j++) {
    const int f = n0 + wn*32 + j*16 + lr;
    const float bg_ = b1[e*2*FDIM + f];
    const float bl_ = b1[e*2*FDIM + FDIM + f];
    #pragma unroll
    for (int i = 0; i < 4; i++) {
      #pragma unroll
      for (int r = 0; r < 4; r++) {
        const int m = wm*64 + i*16 + quad*4 + r;
        if (m0 + m < nt) {
          const float g = accg[i][j][r] + bg_;
          const float l = accl[i][j][r] + bl_;
          const float s = g / (1.f + __expf(-g)) * l;
          act[(size_t)(off + m0 + m)*FDIM + f] = (bf16_t)s;
        }
      }
    }
  }
}

// GEMM2: y = act @ w2^T + b2; out[token] += scale*y  [BM=128, BN=128, splitK x4]
__global__ __launch_bounds__(256, 3) void gemm2_v11(
    const bf16_t* __restrict__ act, const bf16_t* __restrict__ w2bf,
    const float* __restrict__ b2, const int* __restrict__ offsets,
    const int* __restrict__ etok, const float* __restrict__ escale,
    float* __restrict__ out)
{
  const int e   = blockIdx.y;
  const int off = offsets[e];
  const int nt  = offsets[e+1] - off;
  const int m0  = blockIdx.z * 128;
  if (m0 >= nt) return;
  const int n0  = (blockIdx.x >> 2) * 128;
  const int kc  = blockIdx.x & 3;
  const int kbeg = kc * (FDIM/4);          // 512-chunk, 16 iters

  __shared__ __align__(16) bf16_t As[3][128*32];   // 24 KB
  __shared__ __align__(16) bf16_t Bs[3][128*32];   // 24 KB

  const int tid  = threadIdx.x;
  const int w    = tid >> 6, lane = tid & 63;
  const int quad = lane >> 4, lr = lane & 15;
  const int wm   = w >> 1,  wn = w & 1;

  const bf16_t* asrc0; const bf16_t* asrc1;
  int arow0, arow1;
  {
    const int r0 = 0*64 + w*16 + (lane >> 2);
    const int r1 = 1*64 + w*16 + (lane >> 2);
    const int s0 = segswz(lane & 3, r0);
    const int s1 = segswz(lane & 3, r1);
    int e0 = m0 + r0; if (e0 > nt-1) e0 = nt-1;
    int e1 = m0 + r1; if (e1 > nt-1) e1 = nt-1;
    asrc0 = act + (size_t)(off + e0)*FDIM + kbeg + s0*8;
    asrc1 = act + (size_t)(off + e1)*FDIM + kbeg + s1*8;
    arow0 = (0*64 + w*16)*32;
    arow1 = (1*64 + w*16)*32;
  }

  // B staging: wave w covers rows [w*32, +32) via two instructions
  const bf16_t* bsrc0; const bf16_t* bsrc1;
  int bdst0, bdst1;
  {
    const int r0 = w*32 + (lane >> 2);
    const int r1 = w*32 + 16 + (lane >> 2);
    const int s0 = segswz(lane & 3, r0);
    const int s1 = segswz(lane & 3, r1);
    bsrc0 = w2bf + ((size_t)e*HDIM + (size_t)(n0 + r0))*FDIM + kbeg + s0*8;
    bsrc1 = w2bf + ((size_t)e*HDIM + (size_t)(n0 + r1))*FDIM + kbeg + s1*8;
    bdst0 = (w*32)*32;
    bdst1 = (w*32 + 16)*32;
  }

  int aoff[4], boff[4];
  #pragma unroll
  for (int i = 0; i < 4; i++) {
    const int r = wm*64 + i*16 + lr;
    aoff[i] = r*32 + (segswz(quad, r) << 3);
  }
  #pragma unroll
  for (int j = 0; j < 4; j++) {
    const int r = wn*64 + j*16 + lr;
    boff[j] = r*32 + (segswz(quad, r) << 3);
  }

  f32x4 acc[4][4] = {};

#define G2_STAGE(K0, NXT)                                                     \
  { gload16(asrc0 + (K0), &As[NXT][arow0]);                                   \
    gload16(asrc1 + (K0), &As[NXT][arow1]);                                   \
    gload16(bsrc0 + (K0), &Bs[NXT][bdst0]);                                   \
    gload16(bsrc1 + (K0), &Bs[NXT][bdst1]); }

#define G2_MFMA(CUR)                                                          \
  { bf16x8 af[4], bfr[4];                                                     \
    _Pragma("unroll")                                                         \
    for (int i = 0; i < 4; i++) af[i] = *(const bf16x8*)&As[CUR][aoff[i]];    \
    _Pragma("unroll")                                                         \
    for (int j = 0; j < 4; j++) bfr[j] = *(const bf16x8*)&Bs[CUR][boff[j]];   \
    _Pragma("unroll")                                                         \
    for (int i = 0; i < 4; i++)                                               \
      _Pragma("unroll")                                                       \
      for (int j = 0; j < 4; j++)                                             \
        acc[i][j] = __builtin_amdgcn_mfma_f32_16x16x32_bf16(af[i], bfr[j], acc[i][j], 0, 0, 0); }

#define G2_STEP(CUR, NXT)                                                     \
  { G2_STAGE(k0 + 64, NXT);                                                   \
    __builtin_amdgcn_sched_barrier(0);                                        \
    G2_MFMA(CUR);                                                             \
    asm volatile("s_waitcnt vmcnt(4)" ::: "memory");                          \
    __builtin_amdgcn_sched_barrier(0);                                        \
    __builtin_amdgcn_s_barrier();                                             \
    __builtin_amdgcn_sched_barrier(0);                                        \
    k0 += 32; }

  // prologue: stage tiles 0,1
  G2_STAGE(0, 0);
  G2_STAGE(32, 1);
  asm volatile("s_waitcnt vmcnt(4)" ::: "memory");
  __builtin_amdgcn_sched_barrier(0);
  __builtin_amdgcn_s_barrier();
  __builtin_amdgcn_sched_barrier(0);

  int k0 = 0;
  while (k0 < 384) {              // t = 0..11, unrolled x3 (4 passes)
    G2_STEP(0, 2);
    G2_STEP(1, 0);
    G2_STEP(2, 1);
  }
  G2_STEP(0, 2);                  // t = 12: stages tile14 -> buf2
  G2_STEP(1, 0);                  // t = 13: stages tile15 -> buf0
  // t = 14 (buf 2): tile15's stage in flight during MFMA, drain after
  G2_MFMA(2);
  asm volatile("s_waitcnt vmcnt(0)" ::: "memory");
  __builtin_amdgcn_sched_barrier(0);
  __builtin_amdgcn_s_barrier();
  __builtin_amdgcn_sched_barrier(0);
  G2_MFMA(0);                     // t = 15 (buf 0)

#undef G2_STEP
#undef G2_MFMA
#undef G2_STAGE

  // epilogue: + b2 (k-chunk 0 only), scale, atomic scatter-add
  #pragma unroll
  for (int i = 0; i < 4; i++) {
    #pragma unroll
    for (int r = 0; r < 4; r++) {
      const int m = wm*64 + i*16 + quad*4 + r;
      if (m0 + m < nt) {
        const int slot = off + m0 + m;
        const int t    = etok[slot];
        const float s  = escale[slot];
        #pragma unroll
        for (int j = 0; j < 4; j++) {
          const int n = n0 + wn*64 + j*16 + lr;
          float v = acc[i][j][r];
          if (kc == 0) v += b2[e*HDIM + n];
          atomicAdd(&out[(size_t)t*HDIM + n], s * v);
        }
      }
    }
  }
}

// ======== fallback (round-3 fp32-weight kernels, used if ws too small) ====
__global__ __launch_bounds__(256, 3) void gemm1_v8(
    const bf16_t* __restrict__ hbf, const float* __restrict__ w1,
    const float* __restrict__ b1, const int* __restrict__ offsets,
    const int* __restrict__ etok, bf16_t* __restrict__ act)
{
  const int e   = blockIdx.y;
  const int off = offsets[e];
  const int nt  = offsets[e+1] - off;
  const int m0  = blockIdx.z * 128;
  if (m0 >= nt) return;
  const int n0  = blockIdx.x * 64;

  __shared__ __align__(16) bf16_t As[2][128*32];
  __shared__ __align__(16) bf16_t Bg[2][64*32];
  __shared__ __align__(16) bf16_t Bl[2][64*32];

  const int tid  = threadIdx.x;
  const int w    = tid >> 6, lane = tid & 63;
  const int quad = lane >> 4, lr = lane & 15;
  const int wm   = w >> 1,  wn = w & 1;

  const bf16_t* asrc0; const bf16_t* asrc1;
  int arow0, arow1;
  {
    const int r0 = 0*64 + w*16 + (lane >> 2);
    const int r1 = 1*64 + w*16 + (lane >> 2);
    const int s0 = segswz(lane & 3, r0);
    const int s1 = segswz(lane & 3, r1);
    int e0 = m0 + r0; if (e0 > nt-1) e0 = nt-1;
    int e1 = m0 + r1; if (e1 > nt-1) e1 = nt-1;
    asrc0 = hbf + (size_t)etok[off + e0]*HDIM + s0*8;
    asrc1 = hbf + (size_t)etok[off + e1]*HDIM + s1*8;
    arow0 = (0*64 + w*16)*32;
    arow1 = (1*64 + w*16)*32;
  }

  const int br = tid >> 2, bs = tid & 3;
  const float* gsrc = w1 + ((size_t)e*2*FDIM + (size_t)(n0 + br))*HDIM + bs*8;
  const float* lsrc = gsrc + (size_t)FDIM*HDIM;
  const int bofs = br*32 + (segswz(bs, br) << 3);

  int aoff[4], boff[2];
  #pragma unroll
  for (int i = 0; i < 4; i++) {
    const int r = wm*64 + i*16 + lr;
    aoff[i] = r*32 + (segswz(quad, r) << 3);
  }
  #pragma unroll
  for (int j = 0; j < 2; j++) {
    const int r = wn*32 + j*16 + lr;
    boff[j] = r*32 + (segswz(quad, r) << 3);
  }

  f32x4 accg[4][2] = {}, accl[4][2] = {};
  float4 g4[2][2], l4[2][2];

#define F1_LOADB(SET, K0)                                                     \
  { const float4* p_ = (const float4*)(gsrc + (K0));                          \
    g4[SET][0]=p_[0]; g4[SET][1]=p_[1];                                       \
    const float4* q_ = (const float4*)(lsrc + (K0));                          \
    l4[SET][0]=q_[0]; l4[SET][1]=q_[1]; }
#define F1_WRITEB(NXT, SET)                                                   \
  { *(bf16x8*)&Bg[NXT][bofs] = cvt8(g4[SET][0], g4[SET][1]);                  \
    *(bf16x8*)&Bl[NXT][bofs] = cvt8(l4[SET][0], l4[SET][1]); }
#define F1_MFMA(CUR)                                                          \
  { bf16x8 af[4], gf[2], lf[2];                                               \
    _Pragma("unroll")                                                         \
    for (int i = 0; i < 4; i++) af[i] = *(const bf16x8*)&As[CUR][aoff[i]];    \
    _Pragma("unroll")                                                         \
    for (int j = 0; j < 2; j++) {                                             \
      gf[j] = *(const bf16x8*)&Bg[CUR][boff[j]];                              \
      lf[j] = *(const bf16x8*)&Bl[CUR][boff[j]];                              \
    }                                                                         \
    _Pragma("unroll")                                                         \
    for (int i = 0; i < 4; i++)                                               \
      _Pragma("unroll")                                                       \
      for (int j = 0; j < 2; j++) {                                           \
        accg[i][j] = __builtin_amdgcn_mfma_f32_16x16x32_bf16(af[i], gf[j], accg[i][j], 0, 0, 0); \
        accl[i][j] = __builtin_amdgcn_mfma_f32_16x16x32_bf16(af[i], lf[j], accl[i][j], 0, 0, 0); \
      } }

  F1_LOADB(0, 0);
  __builtin_amdgcn_sched_barrier(0);
  gload16(asrc0 + 0, &As[0][arow0]);
  gload16(asrc1 + 0, &As[0][arow1]);
  __builtin_amdgcn_sched_barrier(0);
  F1_WRITEB(0, 0);
  F1_LOADB(0, 32);
  F1_LOADB(1, 64);
  asm volatile("s_waitcnt vmcnt(8) lgkmcnt(0)" ::: "memory");
  __builtin_amdgcn_sched_barrier(0);
  __builtin_amdgcn_s_barrier();
  __builtin_amdgcn_sched_barrier(0);

#define F1_STEP(CUR, SET)                                                     \
  { F1_WRITEB((CUR)^1, SET);                                                  \
    __builtin_amdgcn_sched_barrier(0);                                        \
    gload16(asrc0 + k0 + 32, &As[(CUR)^1][arow0]);                            \
    gload16(asrc1 + k0 + 32, &As[(CUR)^1][arow1]);                            \
    __builtin_amdgcn_sched_barrier(0);                                        \
    F1_LOADB(SET, k0 + 96);                                                   \
    __builtin_amdgcn_sched_barrier(0);                                        \
    F1_MFMA(CUR);                                                             \
    asm volatile("s_waitcnt vmcnt(4) lgkmcnt(0)" ::: "memory");               \
    __builtin_amdgcn_sched_barrier(0);                                        \
    __builtin_amdgcn_s_barrier();                                             \
    __builtin_amdgcn_sched_barrier(0);                                        \
    k0 += 32; }

  int k0 = 0;
  while (k0 < 896) { F1_STEP(0, 0); F1_STEP(1, 1); }
  F1_STEP(0, 0);
  F1_WRITEB(0, 1);
  __builtin_amdgcn_sched_barrier(0);
  gload16(asrc0 + 960, &As[0][arow0]);
  gload16(asrc1 + 960, &As[0][arow1]);
  __builtin_amdgcn_sched_barrier(0);
  F1_MFMA(1);
  asm volatile("s_waitcnt vmcnt(0) lgkmcnt(0)" ::: "memory");
  __builtin_amdgcn_sched_barrier(0);
  __builtin_amdgcn_s_barrier();
  __builtin_amdgcn_sched_barrier(0);
  F1_WRITEB(1, 0);
  __builtin_amdgcn_sched_barrier(0);
  gload16(asrc0 + 992, &As[1][arow0]);
  gload16(asrc1 + 992, &As[1][arow1]);
  __builtin_amdgcn_sched_barrier(0);
  F1_MFMA(0);
  asm volatile("s_waitcnt vmcnt(0) lgkmcnt(0)" ::: "memory");
  __builtin_amdgcn_sched_barrier(0);
  __builtin_amdgcn_s_barrier();
  __builtin_amdgcn_sched_barrier(0);
  F1_MFMA(1);

#undef F1_STEP
#undef F1_MFMA
#undef F1_WRITEB
#undef F1_LOADB

  #pragma unroll
  for (int j = 0; j < 2; j++) {
    const int f = n0 + wn*32 + j*16 + lr;
    const float bg_ = b1[e*2*FDIM + f];
    const float bl_ = b1[e*2*FDIM + FDIM + f];
    #pragma unroll
    for (int i = 0; i < 4; i++) {
      #pragma unroll
      for (int r = 0; r < 4; r++) {
        const int m = wm*64 + i*16 + quad*4 + r;
        if (m0 + m < nt) {
          const float g = accg[i][j][r] + bg_;
          const float l = accl[i][j][r] + bl_;
          const float s = g / (1.f + __expf(-g)) * l;
          act[(size_t)(off + m0 + m)*FDIM + f] = (bf16_t)s;
        }
      }
    }
  }
}

__global__ __launch_bounds__(256, 3) void gemm2_v8(
    const bf16_t* __restrict__ act, const float* __restrict__ w2,
    const float* __restrict__ b2, const int* __restrict__ offsets,
    const int* __restrict__ etok, const float* __restrict__ escale,
    float* __restrict__ out)
{
  const int e   = blockIdx.y;
  const int off = offsets[e];
  const int nt  = offsets[e+1] - off;
  const int m0  = blockIdx.z * 128;
  if (m0 >= nt) return;
  const int n0  = (blockIdx.x >> 2) * 128;
  const int kc  = blockIdx.x & 3;
  const int kbeg = kc * (FDIM/4);

  __shared__ __align__(16) bf16_t As[2][128*32];
  __shared__ __align__(16) bf16_t Bs[2][128*32];

  const int tid  = threadIdx.x;
  const int w    = tid >> 6, lane = tid & 63;
  const int quad = lane >> 4, lr = lane & 15;
  const int wm   = w >> 1,  wn = w & 1;

  const bf16_t* asrc0; const bf16_t* asrc1;
  int arow0, arow1;
  {
    const int r0 = 0*64 + w*16 + (lane >> 2);
    const int r1 = 1*64 + w*16 + (lane >> 2);
    const int s0 = segswz(lane & 3, r0);
    const int s1 = segswz(lane & 3, r1);
    int e0 = m0 + r0; if (e0 > nt-1) e0 = nt-1;
    int e1 = m0 + r1; if (e1 > nt-1) e1 = nt-1;
    asrc0 = act + (size_t)(off + e0)*FDIM + kbeg + s0*8;
    asrc1 = act + (size_t)(off + e1)*FDIM + kbeg + s1*8;
    arow0 = (0*64 + w*16)*32;
    arow1 = (1*64 + w*16)*32;
  }

  const int br = tid >> 1, bc = tid & 1;
  const float* bsrc = w2 + ((size_t)e*HDIM + (size_t)(n0 + br))*FDIM + kbeg + bc*16;
  const int bofs0 = br*32 + (segswz(2*bc,   br) << 3);
  const int bofs1 = br*32 + (segswz(2*bc+1, br) << 3);

  int aoff[4], boff[4];
  #pragma unroll
  for (int i = 0; i < 4; i++) {
    const int r = wm*64 + i*16 + lr;
    aoff[i] = r*32 + (segswz(quad, r) << 3);
  }
  #pragma unroll
  for (int j = 0; j < 4; j++) {
    const int r = wn*64 + j*16 + lr;
    boff[j] = r*32 + (segswz(quad, r) << 3);
  }

  f32x4 acc[4][4] = {};
  float4 b4[2][4];

#define F2_LOADB(SET, K0)                                                     \
  { const float4* p_ = (const float4*)(bsrc + (K0));                          \
    b4[SET][0]=p_[0]; b4[SET][1]=p_[1]; b4[SET][2]=p_[2]; b4[SET][3]=p_[3]; }
#define F2_WRITEB(NXT, SET)                                                   \
  { *(bf16x8*)&Bs[NXT][bofs0] = cvt8(b4[SET][0], b4[SET][1]);                 \
    *(bf16x8*)&Bs[NXT][bofs1] = cvt8(b4[SET][2], b4[SET][3]); }
#define F2_MFMA(CUR)                                                          \
  { bf16x8 af[4], bfr[4];                                                     \
    _Pragma("unroll")                                                         \
    for (int i = 0; i < 4; i++) af[i] = *(const bf16x8*)&As[CUR][aoff[i]];    \
    _Pragma("unroll")                                                         \
    for (int j = 0; j < 4; j++) bfr[j] = *(const bf16x8*)&Bs[CUR][boff[j]];   \
    _Pragma("unroll")                                                         \
    for (int i = 0; i < 4; i++)                                               \
      _Pragma("unroll")                                                       \
      for (int j = 0; j < 4; j++)                                             \
        acc[i][j] = __builtin_amdgcn_mfma_f32_16x16x32_bf16(af[i], bfr[j], acc[i][j], 0, 0, 0); }

  F2_LOADB(0, 0);
  __builtin_amdgcn_sched_barrier(0);
  gload16(asrc0 + 0, &As[0][arow0]);
  gload16(asrc1 + 0, &As[0][arow1]);
  __builtin_amdgcn_sched_barrier(0);
  F2_WRITEB(0, 0);
  F2_LOADB(0, 32);
  F2_LOADB(1, 64);
  asm volatile("s_waitcnt vmcnt(8) lgkmcnt(0)" ::: "memory");
  __builtin_amdgcn_sched_barrier(0);
  __builtin_amdgcn_s_barrier();
  __builtin_amdgcn_sched_barrier(0);

#define F2_STEP(CUR, SET)                                                     \
  { F2_WRITEB((CUR)^1, SET);                                                  \
    __builtin_amdgcn_sched_barrier(0);                                        \
    gload16(asrc0 + k0 + 32, &As[(CUR)^1][arow0]);                            \
    gload16(asrc1 + k0 + 32, &As[(CUR)^1][arow1]);                            \
    __builtin_amdgcn_sched_barrier(0);                                        \
    F2_LOADB(SET, k0 + 96);                                                   \
    __builtin_amdgcn_sched_barrier(0);                                        \
    F2_MFMA(CUR);                                                             \
    asm volatile("s_waitcnt vmcnt(4) lgkmcnt(0)" ::: "memory");               \
    __builtin_amdgcn_sched_barrier(0);                                        \
    __builtin_amdgcn_s_barrier();                                             \
    __builtin_amdgcn_sched_barrier(0);                                        \
    k0 += 32; }

  int k0 = 0;
  while (k0 < 384) { F2_STEP(0, 0); F2_STEP(1, 1); }
  F2_STEP(0, 0);
  F2_WRITEB(0, 1);
  __builtin_amdgcn_sched_barrier(0);
  gload16(asrc0 + 448, &As[0][arow0]);
  gload16(asrc1 + 448, &As[0][arow1]);
  __builtin_amdgcn_sched_barrier(0);
  F2_MFMA(1);
  asm volatile("s_waitcnt vmcnt(0) lgkmcnt(0)" ::: "memory");
  __builtin_amdgcn_sched_barrier(0);
  __builtin_amdgcn_s_barrier();
  __builtin_amdgcn_sched_barrier(0);
  F2_WRITEB(1, 0);
  __builtin_amdgcn_sched_barrier(0);
  gload16(asrc0 + 480, &As[1][arow0]);
  gload16(asrc1 + 480, &As[1][arow1]);
  __builtin_amdgcn_sched_barrier(0);
  F2_MFMA(0);
  asm volatile("s_waitcnt vmcnt(0) lgkmcnt(0)" ::: "memory");
  __builtin_amdgcn_sched_barrier(0);
  __builtin_amdgcn_s_barrier();
  __builtin_amdgcn_sched_barrier(0);
  F2_MFMA(1);

#undef F2_STEP
#undef F2_MFMA
#undef F2_WRITEB
#undef F2_LOADB

  #pragma unroll
  for (int i = 0; i < 4; i++) {
    #pragma unroll
    for (int r = 0; r < 4; r++) {
      const int m = wm*64 + i*16 + quad*4 + r;
      if (m0 + m < nt) {
        const int slot = off + m0 + m;
        const int t    = etok[slot];
        const float s  = escale[slot];
        #pragma unroll
        for (int j = 0; j < 4; j++) {
          const int n = n0 + wn*64 + j*16 + lr;
          float v = acc[i][j][r];
          if (kc == 0) v += b2[e*HDIM + n];
          atomicAdd(&out[(size_t)t*HDIM + n], s * v);
        }
      }
    }
  }
}

extern "C" void kernel_launch(void* const* d_in, const int* in_sizes, int n_in,
                              void* d_out, int out_size, void* d_ws, size_t ws_size,
                              hipStream_t stream) {
  const float* hidden = (const float*)d_in[0];
  const int*   sel    = (const int*)d_in[1];
  const float* scal   = (const float*)d_in[2];
  const float* w1     = (const float*)d_in[3];
  const float* b1     = (const float*)d_in[4];
  const float* w2     = (const float*)d_in[5];
  const float* b2     = (const float*)d_in[6];
  float* out = (float*)d_out;

  char* ws = (char*)d_ws;
  int*    offsets = (int*)(ws + WB_OFFSETS);
  int*    etok    = (int*)(ws + WB_ETOK);
  float*  escale  = (float*)(ws + WB_ESCALE);
  bf16_t* act     = (bf16_t*)(ws + WB_ACT);
  bf16_t* hbf     = (bf16_t*)(ws + WB_H);
  bf16_t* w2bf    = (bf16_t*)(ws + WB_W2BF);
  bf16_t* w1bf    = (bf16_t*)(ws + WB_W1BF);

  hipMemsetAsync(d_out, 0, (size_t)out_size * sizeof(float), stream);

  route_all<<<1, 256, 0, stream>>>(sel, scal, offsets, etok, escale);
  convert_h<<<(int)(H_ELEMS/8/256), 256, 0, stream>>>(hidden, hbf);

  if (ws_size >= WB_NEED) {
    // bf16-weight path: streaming converters, then depth-2 pipelined GEMMs.
    convert_h<<<(int)(W2_ELEMS/8/256), 256, 0, stream>>>(w2, w2bf);
    convert_h<<<(int)(W1_ELEMS/8/256), 256, 0, stream>>>(w1, w1bf);
    gemm1_v11<<<dim3(FDIM/64, NEXP, NENT/128), 256, 0, stream>>>(hbf, w1bf, b1, offsets, etok, act);
    gemm2_v11<<<dim3((HDIM/128)*4, NEXP, NENT/128), 256, 0, stream>>>(act, w2bf, b2, offsets, etok, escale, out);
  } else {
    // fallback: round-3 fp32-weight kernels
    gemm1_v8<<<dim3(FDIM/64, NEXP, NENT/128), 256, 0, stream>>>(hbf, w1, b1, offsets, etok, act);
    gemm2_v8<<<dim3((HDIM/128)*4, NEXP, NENT/128), 256, 0, stream>>>(act, w2, b2, offsets, etok, escale, out);
  }
}